// Round 1
// baseline (256.556 us; speedup 1.0000x reference)
//
#include <hip/hip_runtime.h>
#include <cstdint>

typedef __attribute__((ext_vector_type(8))) short short8;
typedef __attribute__((ext_vector_type(4))) float f32x4;

__device__ __forceinline__ unsigned short bf16_rtne(float f) {
    unsigned int u = __float_as_uint(f);
    unsigned int r = (u + 0x7fffu + ((u >> 16) & 1u)) >> 16;
    return (unsigned short)r;
}
__device__ __forceinline__ float bf16_tof(unsigned short h) {
    return __uint_as_float(((unsigned int)h) << 16);
}

// ---------------- weight prep: split fp32 weights into bf16 hi/lo ----------------
// layers 0-2: cond_Wh[3][64][64], 3: cond_Wo[64][64], 4-6: scale_Wh, 7: scale_Wo
__global__ void prep_weights_kernel(const float* __restrict__ cWh,
                                    const float* __restrict__ cWo,
                                    const float* __restrict__ sWh,
                                    const float* __restrict__ sWo,
                                    unsigned short* __restrict__ whi,
                                    unsigned short* __restrict__ wlo) {
    int idx = blockIdx.x * 256 + threadIdx.x;  // 0..32767
    int layer = idx >> 12;
    int e = idx & 4095;
    const float* src;
    if (layer < 3)       src = cWh + layer * 4096;
    else if (layer == 3) src = cWo;
    else if (layer < 7)  src = sWh + (layer - 4) * 4096;
    else                 src = sWo;
    float w = src[e];
    unsigned short hi = bf16_rtne(w);
    float lo = w - bf16_tof(hi);
    whi[idx] = hi;
    wlo[idx] = bf16_rtne(lo);
}

// ---------------- LDS staging helpers ----------------
// Per-wave plane: [64 samples][64 feats] bf16, 128B rows, 16B chunks XOR-swizzled
// by (sample&7) to kill the 128B-stride bank conflict.
__device__ __forceinline__ short8 lds_read8(const unsigned short* P, int s, int k0) {
    int ch = (k0 >> 3) ^ (s & 7);
    return *(const short8*)(P + s * 64 + ch * 8);
}
__device__ __forceinline__ void lds_write4(unsigned short* P, int s, int f0,
                                           unsigned short a, unsigned short b,
                                           unsigned short cc, unsigned short d) {
    int ch = (f0 >> 3) ^ (s & 7);
    uint2 w;
    w.x = (unsigned int)a | ((unsigned int)b << 16);
    w.y = (unsigned int)cc | ((unsigned int)d << 16);
    *(uint2*)(P + s * 64 + ch * 8 + (f0 & 7)) = w;
}
__device__ __forceinline__ void stage_frag(unsigned short* Phi, unsigned short* Plo,
                                           int s, int f0, f32x4 v) {
    unsigned short h0 = bf16_rtne(v[0]), h1 = bf16_rtne(v[1]),
                   h2 = bf16_rtne(v[2]), h3 = bf16_rtne(v[3]);
    lds_write4(Phi, s, f0, h0, h1, h2, h3);
    unsigned short l0 = bf16_rtne(v[0] - bf16_tof(h0)),
                   l1 = bf16_rtne(v[1] - bf16_tof(h1)),
                   l2 = bf16_rtne(v[2] - bf16_tof(h2)),
                   l3 = bf16_rtne(v[3] - bf16_tof(h3));
    lds_write4(Plo, s, f0, l0, l1, l2, l3);
}

// ---------------- one MLP layer: acc[feat_tile][sample_tile] = W @ h^T + b ----------------
// D = A*B: A = weights [16 out-feats x 32 k] frags, B = h^T from staging
// (lane: sample = l&15, k = ks*32 + 8*(l>>4) + e contiguous).
// 3-term split-precision: Ah*Bh + Al*Bh + Ah*Bl.
__device__ __forceinline__ void mlp_layer(const unsigned short* Phi, const unsigned short* Plo,
                                          const unsigned short* Whi, const unsigned short* Wlo,
                                          const float* __restrict__ bias,
                                          int c, int g, f32x4 acc[4][4]) {
    short8 ah[4][2], al[4][2];
#pragma unroll
    for (int mt = 0; mt < 4; ++mt)
#pragma unroll
        for (int ks = 0; ks < 2; ++ks) {
            int off = (mt * 16 + c) * 64 + ks * 32 + 8 * g;
            ah[mt][ks] = *(const short8*)(Whi + off);
            al[mt][ks] = *(const short8*)(Wlo + off);
        }
#pragma unroll
    for (int mt = 0; mt < 4; ++mt) {
        f32x4 b = *(const f32x4*)(bias + mt * 16 + 4 * g);  // acc row r -> feat mt*16+4g+r
#pragma unroll
        for (int nt = 0; nt < 4; ++nt) acc[mt][nt] = b;
    }
#pragma unroll
    for (int nt = 0; nt < 4; ++nt) {
        int s = nt * 16 + c;
#pragma unroll
        for (int ks = 0; ks < 2; ++ks) {
            short8 bh = lds_read8(Phi, s, ks * 32 + 8 * g);
            short8 bl = lds_read8(Plo, s, ks * 32 + 8 * g);
#pragma unroll
            for (int mt = 0; mt < 4; ++mt) {
                acc[mt][nt] = __builtin_amdgcn_mfma_f32_16x16x32_bf16(ah[mt][ks], bh, acc[mt][nt], 0, 0, 0);
                acc[mt][nt] = __builtin_amdgcn_mfma_f32_16x16x32_bf16(al[mt][ks], bh, acc[mt][nt], 0, 0, 0);
                acc[mt][nt] = __builtin_amdgcn_mfma_f32_16x16x32_bf16(ah[mt][ks], bl, acc[mt][nt], 0, 0, 0);
            }
        }
    }
}

__device__ __forceinline__ void write_h_relu(unsigned short* Phi, unsigned short* Plo,
                                             f32x4 acc[4][4], int c, int g) {
#pragma unroll
    for (int mt = 0; mt < 4; ++mt)
#pragma unroll
        for (int nt = 0; nt < 4; ++nt) {
            f32x4 v = acc[mt][nt];
#pragma unroll
            for (int i = 0; i < 4; ++i) v[i] = fmaxf(v[i], 0.f);
            stage_frag(Phi, Plo, nt * 16 + c, mt * 16 + 4 * g, v);
        }
}

// ---------------- main kernel: one wave owns 64 rows, no block barriers ----------------
__global__ __launch_bounds__(256, 2)
void coupling_main_kernel(const float* __restrict__ x,
                          const float* __restrict__ cbh, const float* __restrict__ cbo,
                          const float* __restrict__ sbh, const float* __restrict__ sbo,
                          const unsigned short* __restrict__ whi,
                          const unsigned short* __restrict__ wlo,
                          float* __restrict__ y, float* __restrict__ logdet) {
    __shared__ unsigned short stage[4][2][4096];  // 4 waves x (hi,lo) x 64x64 bf16 = 64 KB
    const int lane = threadIdx.x & 63;
    const int wid = threadIdx.x >> 6;
    const int c = lane & 15;
    const int g = lane >> 4;
    unsigned short* Phi = &stage[wid][0][0];
    unsigned short* Plo = &stage[wid][1][0];
    const long row0 = ((long)blockIdx.x * 4 + wid) * 64;

    // prologue: read x_masked once, pass through to y[:, :64], stage bf16 hi/lo
#pragma unroll
    for (int nt = 0; nt < 4; ++nt) {
        const int s = nt * 16 + c;
        const long r = (row0 + s) * 128;
#pragma unroll
        for (int mt = 0; mt < 4; ++mt) {
            const int f0 = mt * 16 + 4 * g;
            f32x4 v = *(const f32x4*)(x + r + f0);
            *(f32x4*)(y + r + f0) = v;
            stage_frag(Phi, Plo, s, f0, v);
        }
    }

    f32x4 acc[4][4];

    // scale MLP layer 0 first (staging still holds x); park h_s in registers
    mlp_layer(Phi, Plo, whi + 4 * 4096, wlo + 4 * 4096, sbh, c, g, acc);
    f32x4 hs[4][4];
#pragma unroll
    for (int mt = 0; mt < 4; ++mt)
#pragma unroll
        for (int nt = 0; nt < 4; ++nt) {
            f32x4 v = acc[mt][nt];
#pragma unroll
            for (int i = 0; i < 4; ++i) v[i] = fmaxf(v[i], 0.f);
            hs[mt][nt] = v;
        }

    // cond MLP: layers 0-2 relu, layer 3 linear -> shift
    mlp_layer(Phi, Plo, whi, wlo, cbh, c, g, acc);
    write_h_relu(Phi, Plo, acc, c, g);
    mlp_layer(Phi, Plo, whi + 1 * 4096, wlo + 1 * 4096, cbh + 64, c, g, acc);
    write_h_relu(Phi, Plo, acc, c, g);
    mlp_layer(Phi, Plo, whi + 2 * 4096, wlo + 2 * 4096, cbh + 128, c, g, acc);
    write_h_relu(Phi, Plo, acc, c, g);
    mlp_layer(Phi, Plo, whi + 3 * 4096, wlo + 3 * 4096, cbo, c, g, acc);
    f32x4 shiftv[4][4];
#pragma unroll
    for (int mt = 0; mt < 4; ++mt)
#pragma unroll
        for (int nt = 0; nt < 4; ++nt) shiftv[mt][nt] = acc[mt][nt];

    // un-park h_s into staging, finish scale MLP
#pragma unroll
    for (int mt = 0; mt < 4; ++mt)
#pragma unroll
        for (int nt = 0; nt < 4; ++nt)
            stage_frag(Phi, Plo, nt * 16 + c, mt * 16 + 4 * g, hs[mt][nt]);
    mlp_layer(Phi, Plo, whi + 5 * 4096, wlo + 5 * 4096, sbh + 64, c, g, acc);
    write_h_relu(Phi, Plo, acc, c, g);
    mlp_layer(Phi, Plo, whi + 6 * 4096, wlo + 6 * 4096, sbh + 128, c, g, acc);
    write_h_relu(Phi, Plo, acc, c, g);
    mlp_layer(Phi, Plo, whi + 7 * 4096, wlo + 7 * 4096, sbo, c, g, acc);  // log_scale

    // epilogue: y[:,64:] = x_t * exp(clip(ls,-5,3)) + shift ; logdet = sum(ls unclipped)
    float pld[4] = {0.f, 0.f, 0.f, 0.f};
#pragma unroll
    for (int nt = 0; nt < 4; ++nt) {
        const int s = nt * 16 + c;
        const long r = (row0 + s) * 128;
#pragma unroll
        for (int mt = 0; mt < 4; ++mt) {
            const int f0 = mt * 16 + 4 * g;
            f32x4 ls = acc[mt][nt];
            pld[nt] += ls[0] + ls[1] + ls[2] + ls[3];
            f32x4 xt = *(const f32x4*)(x + r + 64 + f0);
            f32x4 out;
#pragma unroll
            for (int i = 0; i < 4; ++i) {
                float cl = fminf(fmaxf(ls[i], -5.f), 3.f);
                float sc = __expf(cl);
                out[i] = xt[i] * sc + shiftv[mt][nt][i];
            }
            *(f32x4*)(y + r + 64 + f0) = out;
        }
    }
#pragma unroll
    for (int nt = 0; nt < 4; ++nt) {
        float v = pld[nt];
        v += __shfl_xor(v, 16);
        v += __shfl_xor(v, 32);
        if (g == 0) logdet[row0 + nt * 16 + c] = v;
    }
}

extern "C" void kernel_launch(void* const* d_in, const int* in_sizes, int n_in,
                              void* d_out, int out_size, void* d_ws, size_t ws_size,
                              hipStream_t stream) {
    const float* x   = (const float*)d_in[0];
    const float* cWh = (const float*)d_in[1];
    const float* cbh = (const float*)d_in[2];
    const float* cWo = (const float*)d_in[3];
    const float* cbo = (const float*)d_in[4];
    const float* sWh = (const float*)d_in[5];
    const float* sbh = (const float*)d_in[6];
    const float* sWo = (const float*)d_in[7];
    const float* sbo = (const float*)d_in[8];

    const int B = in_sizes[0] / 128;  // 524288

    unsigned short* whi = (unsigned short*)d_ws;
    unsigned short* wlo = whi + 8 * 4096;

    prep_weights_kernel<<<128, 256, 0, stream>>>(cWh, cWo, sWh, sWo, whi, wlo);

    float* y = (float*)d_out;
    float* logdet = y + (size_t)B * 128;
    const int blocks = B / 256;  // 64 rows/wave * 4 waves/block
    coupling_main_kernel<<<blocks, 256, 0, stream>>>(x, cbh, cbo, sbh, sbo, whi, wlo, y, logdet);
}

// Round 2
// 174.347 us; speedup vs baseline: 1.4715x; 1.4715x over previous
//
#include <hip/hip_runtime.h>
#include <hip/hip_bf16.h>
#include <cstdint>

typedef __attribute__((ext_vector_type(8))) short short8;
typedef __attribute__((ext_vector_type(4))) float f32x4;
typedef __attribute__((ext_vector_type(4))) unsigned int u32x4;

// pack two floats as bf16 pair (RTNE), a in low 16, b in high 16
__device__ __forceinline__ uint32_t pk_bf16(float a, float b) {
    uint32_t ua = (uint32_t)__builtin_bit_cast(unsigned short, __float2bfloat16(a));
    uint32_t ub = (uint32_t)__builtin_bit_cast(unsigned short, __float2bfloat16(b));
    return ua | (ub << 16);
}
// split (a,b) into bf16 hi pair H and bf16 lo pair L (3-term split precision)
__device__ __forceinline__ void split_pair(float a, float b, uint32_t& H, uint32_t& L) {
    H = pk_bf16(a, b);
    float fa = __uint_as_float(H << 16);
    float fb = __uint_as_float(H & 0xffff0000u);
    L = pk_bf16(a - fa, b - fb);
}
__device__ __forceinline__ short8 mk8(uint32_t a, uint32_t b, uint32_t c, uint32_t d) {
    u32x4 v; v[0] = a; v[1] = b; v[2] = c; v[3] = d;
    return __builtin_bit_cast(short8, v);
}
// build B-frag pair (hi,lo) from two acc tiles (k-tiles 2kp, 2kp+1)
__device__ __forceinline__ void cvt_frag(f32x4 A, f32x4 Bv, short8& hi, short8& lo) {
    uint32_t h0, l0, h1, l1, h2, l2, h3, l3;
    split_pair(A[0],  A[1],  h0, l0);
    split_pair(A[2],  A[3],  h1, l1);
    split_pair(Bv[0], Bv[1], h2, l2);
    split_pair(Bv[2], Bv[3], h3, l3);
    hi = mk8(h0, h1, h2, h3);
    lo = mk8(l0, l1, l2, l3);
}

// ---------------- weight prep: fp32 W -> permuted-K bf16 hi/lo A-fragments ----------------
// k-slot (g,e) of k-step kp holds feature f = (2kp + (e>>2))*16 + 4g + (e&3).
// Layout: wf[(Lid*2+kp)*2 + plane][lane][mt][e]  (2048 elems per plane-frag)
__global__ void prep_weights(const float* __restrict__ cWh, const float* __restrict__ cWo,
                             const float* __restrict__ sWh, const float* __restrict__ sWo,
                             unsigned short* __restrict__ wf) {
    int t = blockIdx.x * 256 + threadIdx.x;  // 0..32767
    int e    = t & 7;
    int mt   = (t >> 3) & 3;
    int lane = (t >> 5) & 63;
    int kp   = (t >> 11) & 1;
    int L    = (t >> 12) & 7;
    const float* src = (L < 3)  ? cWh + L * 4096
                     : (L == 3) ? cWo
                     : (L < 7)  ? sWh + (L - 4) * 4096
                     :            sWo;
    int m = mt * 16 + (lane & 15);
    int k = (2 * kp + (e >> 2)) * 16 + 4 * (lane >> 4) + (e & 3);
    float w = src[m * 64 + k];
    uint32_t H, Lo;
    split_pair(w, w, H, Lo);
    int off = lane * 32 + mt * 8 + e;
    int fi = (L * 2 + kp) * 2;
    wf[fi * 2048 + off]        = (unsigned short)H;   // hi plane
    wf[(fi + 1) * 2048 + off]  = (unsigned short)Lo;  // lo plane
}

// ---------------- one MLP layer, all in registers ----------------
__device__ __forceinline__ void run_layer(const unsigned short* __restrict__ wf, int Lid,
                                          const float* __restrict__ bias, int lane, int g4,
                                          const short8 Bh[2][4], const short8 Bl[2][4],
                                          f32x4 acc[4][4]) {
#pragma unroll
    for (int mt = 0; mt < 4; ++mt) {
        f32x4 bb = *(const f32x4*)(bias + mt * 16 + g4);
#pragma unroll
        for (int nt = 0; nt < 4; ++nt) acc[mt][nt] = bb;
    }
#pragma unroll
    for (int kp = 0; kp < 2; ++kp) {
        short8 Ah[4], Al[4];
        const unsigned short* p = wf + (Lid * 2 + kp) * 4096 + lane * 32;
#pragma unroll
        for (int mt = 0; mt < 4; ++mt) {
            Ah[mt] = *(const short8*)(p + mt * 8);
            Al[mt] = *(const short8*)(p + 2048 + mt * 8);
        }
#pragma unroll
        for (int nt = 0; nt < 4; ++nt)
#pragma unroll
            for (int mt = 0; mt < 4; ++mt) {
                acc[mt][nt] = __builtin_amdgcn_mfma_f32_16x16x32_bf16(Ah[mt], Bh[kp][nt], acc[mt][nt], 0, 0, 0);
                acc[mt][nt] = __builtin_amdgcn_mfma_f32_16x16x32_bf16(Al[mt], Bh[kp][nt], acc[mt][nt], 0, 0, 0);
                acc[mt][nt] = __builtin_amdgcn_mfma_f32_16x16x32_bf16(Ah[mt], Bl[kp][nt], acc[mt][nt], 0, 0, 0);
            }
    }
}

template<bool RELU>
__device__ __forceinline__ void acc_to_B(const f32x4 acc[4][4], short8 Bh[2][4], short8 Bl[2][4]) {
#pragma unroll
    for (int kp = 0; kp < 2; ++kp)
#pragma unroll
        for (int nt = 0; nt < 4; ++nt) {
            f32x4 a = acc[2 * kp][nt], b = acc[2 * kp + 1][nt];
            if (RELU) {
#pragma unroll
                for (int i = 0; i < 4; ++i) { a[i] = fmaxf(a[i], 0.f); b[i] = fmaxf(b[i], 0.f); }
            }
            cvt_frag(a, b, Bh[kp][nt], Bl[kp][nt]);
        }
}

// ---------------- main kernel: 1 wave = 64 rows, no LDS, no barriers ----------------
__global__ __launch_bounds__(64, 2)
void coupling_main(const float* __restrict__ x,
                   const float* __restrict__ cbh, const float* __restrict__ cbo,
                   const float* __restrict__ sbh, const float* __restrict__ sbo,
                   const unsigned short* __restrict__ wf,
                   float* __restrict__ y, float* __restrict__ logdet) {
    const int lane = threadIdx.x;
    const int c = lane & 15;
    const int g4 = (lane >> 4) * 4;
    const long row0 = (long)blockIdx.x * 64;
    const float* xr = x + (row0 + c) * 128 + g4;
    float* yr = y + (row0 + c) * 128 + g4;

    // prologue: read x_masked once, pass through to y[:, :64], build B0 frags
    f32x4 xm[4][4];
#pragma unroll
    for (int nt = 0; nt < 4; ++nt)
#pragma unroll
        for (int kt = 0; kt < 4; ++kt)
            xm[nt][kt] = *(const f32x4*)(xr + nt * 2048 + kt * 16);
#pragma unroll
    for (int nt = 0; nt < 4; ++nt)
#pragma unroll
        for (int kt = 0; kt < 4; ++kt)
            *(f32x4*)(yr + nt * 2048 + kt * 16) = xm[nt][kt];

    short8 B0h[2][4], B0l[2][4];
#pragma unroll
    for (int kp = 0; kp < 2; ++kp)
#pragma unroll
        for (int nt = 0; nt < 4; ++nt)
            cvt_frag(xm[nt][2 * kp], xm[nt][2 * kp + 1], B0h[kp][nt], B0l[kp][nt]);

    f32x4 acc[4][4];
    short8 Bh[2][4], Bl[2][4];

    // cond MLP (prep layer ids 0..3) -> shift
    run_layer(wf, 0, cbh,       lane, g4, B0h, B0l, acc);
    acc_to_B<true>(acc, Bh, Bl);
    run_layer(wf, 1, cbh + 64,  lane, g4, Bh, Bl, acc);
    acc_to_B<true>(acc, Bh, Bl);
    run_layer(wf, 2, cbh + 128, lane, g4, Bh, Bl, acc);
    acc_to_B<true>(acc, Bh, Bl);
    run_layer(wf, 3, cbo,       lane, g4, Bh, Bl, acc);
    f32x4 shift[4][4];
#pragma unroll
    for (int mt = 0; mt < 4; ++mt)
#pragma unroll
        for (int nt = 0; nt < 4; ++nt) shift[mt][nt] = acc[mt][nt];

    // scale MLP (ids 4..7) -> log_scale in acc
    run_layer(wf, 4, sbh,       lane, g4, B0h, B0l, acc);
    acc_to_B<true>(acc, Bh, Bl);
    run_layer(wf, 5, sbh + 64,  lane, g4, Bh, Bl, acc);
    acc_to_B<true>(acc, Bh, Bl);
    run_layer(wf, 6, sbh + 128, lane, g4, Bh, Bl, acc);
    acc_to_B<true>(acc, Bh, Bl);
    run_layer(wf, 7, sbo,       lane, g4, Bh, Bl, acc);

    // epilogue
    f32x4 xt[4][4];
#pragma unroll
    for (int nt = 0; nt < 4; ++nt)
#pragma unroll
        for (int mt = 0; mt < 4; ++mt)
            xt[nt][mt] = *(const f32x4*)(xr + nt * 2048 + 64 + mt * 16);

    float pld0 = 0.f, pld1 = 0.f, pld2 = 0.f, pld3 = 0.f;
#pragma unroll
    for (int nt = 0; nt < 4; ++nt) {
        float psum = 0.f;
#pragma unroll
        for (int mt = 0; mt < 4; ++mt) {
            f32x4 ls = acc[mt][nt];
            psum += ls[0] + ls[1] + ls[2] + ls[3];
            f32x4 o;
#pragma unroll
            for (int i = 0; i < 4; ++i) {
                float cl = fminf(fmaxf(ls[i], -5.f), 3.f);
                o[i] = xt[nt][mt][i] * __expf(cl) + shift[mt][nt][i];
            }
            *(f32x4*)(yr + nt * 2048 + 64 + mt * 16) = o;
        }
        if (nt == 0) pld0 = psum; else if (nt == 1) pld1 = psum;
        else if (nt == 2) pld2 = psum; else pld3 = psum;
    }
#pragma unroll
    for (int nt = 0; nt < 4; ++nt) {
        float v = (nt == 0) ? pld0 : (nt == 1) ? pld1 : (nt == 2) ? pld2 : pld3;
        v += __shfl_xor(v, 16);
        v += __shfl_xor(v, 32);
        if ((lane >> 4) == 0) logdet[row0 + nt * 16 + c] = v;
    }
}

extern "C" void kernel_launch(void* const* d_in, const int* in_sizes, int n_in,
                              void* d_out, int out_size, void* d_ws, size_t ws_size,
                              hipStream_t stream) {
    const float* x   = (const float*)d_in[0];
    const float* cWh = (const float*)d_in[1];
    const float* cbh = (const float*)d_in[2];
    const float* cWo = (const float*)d_in[3];
    const float* cbo = (const float*)d_in[4];
    const float* sWh = (const float*)d_in[5];
    const float* sbh = (const float*)d_in[6];
    const float* sWo = (const float*)d_in[7];
    const float* sbo = (const float*)d_in[8];

    const int B = in_sizes[0] / 128;  // 524288

    unsigned short* wf = (unsigned short*)d_ws;  // 8 layers * 2 kp * 2 planes * 2048 = 128 KB

    prep_weights<<<128, 256, 0, stream>>>(cWh, cWo, sWh, sWo, wf);

    float* y = (float*)d_out;
    float* logdet = y + (size_t)B * 128;
    coupling_main<<<B / 64, 64, 0, stream>>>(x, cbh, cbo, sbh, sbo, wf, y, logdet);
}